// Round 5
// baseline (64.855 us; speedup 1.0000x reference)
//
#include <hip/hip_runtime.h>
#include <hip/hip_bf16.h>

#define BB 4096
#define DD 512

typedef unsigned short u16;
typedef unsigned int u32;

using f32x4 = __attribute__((ext_vector_type(4))) float;
using bf16x8 = __attribute__((ext_vector_type(8))) short;

// exp scaling: p = exp2((s-1)*100*log2e + 64)  -> all normal-range for s in [-0.44, 1]
// lse = 100 - 64*ln2 + ln(sum p)
constexpr float CEXP = 144.26950408889634f;          // 100 * log2(e)
constexpr float EOFF = 64.0f - 144.26950408889634f;  // bias - CEXP
constexpr float LN2 = 0.6931471805599453f;
constexpr float LSE_BASE = 100.0f - 64.0f * 0.6931471805599453f;

__device__ __forceinline__ float wave_sum(float v) {
#pragma unroll
  for (int m = 1; m < 64; m <<= 1) v += __shfl_xor(v, m);
  return v;
}

__device__ __forceinline__ u16 f2bf(float f) {
  __hip_bfloat16 h = __float2bfloat16(f);
  return __builtin_bit_cast(u16, h);
}

// async global->LDS, 16B per lane. LDS dest is wave-uniform base + lane*16.
__device__ __forceinline__ void gload16(const u16* g, const u16* l) {
  __builtin_amdgcn_global_load_lds(
      (const __attribute__((address_space(1))) void*)g,
      (__attribute__((address_space(3))) void*)(const_cast<u16*>(l)), 16, 0, 0);
}

// raw barrier (no vmcnt(0)/lgkmcnt(0) drain); memory clobbers keep LDS ops on their side
__device__ __forceinline__ void barrier_raw() {
  asm volatile("" ::: "memory");
  __builtin_amdgcn_s_barrier();
  asm volatile("" ::: "memory");
}

// ---------------- kernel 1: row L2-normalize (fp32) -> bf16, plus fp32 pos ----------------
__global__ __launch_bounds__(256) void k_norm(const float* __restrict__ feat,
                                              const float* __restrict__ feat_old,
                                              u16* __restrict__ fnb, u16* __restrict__ fob,
                                              float* __restrict__ pos) {
  const int i = blockIdx.x * 4 + (threadIdx.x >> 6);
  const int t = threadIdx.x & 63;
  const float4 x0 = *(const float4*)(feat + (size_t)i * DD + t * 4);
  const float4 x1 = *(const float4*)(feat + (size_t)i * DD + 256 + t * 4);
  const float4 y0 = *(const float4*)(feat_old + (size_t)i * DD + t * 4);
  const float4 y1 = *(const float4*)(feat_old + (size_t)i * DD + 256 + t * 4);
  float sx = x0.x * x0.x + x0.y * x0.y + x0.z * x0.z + x0.w * x0.w +
             x1.x * x1.x + x1.y * x1.y + x1.z * x1.z + x1.w * x1.w;
  float sy = y0.x * y0.x + y0.y * y0.y + y0.z * y0.z + y0.w * y0.w +
             y1.x * y1.x + y1.y * y1.y + y1.z * y1.z + y1.w * y1.w;
  float sxy = x0.x * y0.x + x0.y * y0.y + x0.z * y0.z + x0.w * y0.w +
              x1.x * y1.x + x1.y * y1.y + x1.z * y1.z + x1.w * y1.w;
  sx = wave_sum(sx);
  sy = wave_sum(sy);
  sxy = wave_sum(sxy);
  const float inx = 1.0f / fmaxf(sqrtf(sx), 1e-12f);
  const float iny = 1.0f / fmaxf(sqrtf(sy), 1e-12f);
  ushort4 ox0, ox1, oy0, oy1;
  ox0.x = f2bf(x0.x * inx); ox0.y = f2bf(x0.y * inx);
  ox0.z = f2bf(x0.z * inx); ox0.w = f2bf(x0.w * inx);
  ox1.x = f2bf(x1.x * inx); ox1.y = f2bf(x1.y * inx);
  ox1.z = f2bf(x1.z * inx); ox1.w = f2bf(x1.w * inx);
  oy0.x = f2bf(y0.x * iny); oy0.y = f2bf(y0.y * iny);
  oy0.z = f2bf(y0.z * iny); oy0.w = f2bf(y0.w * iny);
  oy1.x = f2bf(y1.x * iny); oy1.y = f2bf(y1.y * iny);
  oy1.z = f2bf(y1.z * iny); oy1.w = f2bf(y1.w * iny);
  *(ushort4*)(fnb + (size_t)i * DD + t * 4) = ox0;
  *(ushort4*)(fnb + (size_t)i * DD + 256 + t * 4) = ox1;
  *(ushort4*)(fob + (size_t)i * DD + t * 4) = oy0;
  *(ushort4*)(fob + (size_t)i * DD + 256 + t * 4) = oy1;
  if (t == 0) pos[i] = sxy * inx * iny;
}

// ---------------- kernel 2: fused dual-GEMM, XCD-rect + 4-phase pipeline ----------------
// 512 blocks; XCD x (blockIdx%8) owns rects {x, x+8}, rect = 4mt x 8nt (3MB, L2-fit).
// 512 threads = 8 waves (2M x 4N); per-wave output 128x64 of the 256x256 virtual tile
// (N cols 0-127 = B1/old = n2o, 128-255 = B2/new = n2n). BK=64, LDS double-buffered.
// Per K-tile: 4 phases {ds-read subtile ∥ stage half-tile -> barrier -> 16 MFMA -> barrier},
// vmcnt gate (2) once per K-tile; loads never drained mid-loop.
__global__ __launch_bounds__(512, 2) void k_fused(const u16* __restrict__ fnb,
                                                  const u16* __restrict__ fob,
                                                  const int* __restrict__ tgt,
                                                  float* __restrict__ partial) {
  __shared__ __align__(16) u16 lA[2 * 256 * 64];  // 64 KB
  __shared__ __align__(16) u16 lB[2 * 256 * 64];  // 64 KB (rows 0-127 B1, 128-255 B2)

  const int tid = threadIdx.x;
  const int lane = tid & 63;
  const int wid = tid >> 6;  // 0..7
  const int wm = wid >> 2;   // 0..1  M half (128 rows)
  const int wn = wid & 3;    // 0..3  N quarter (64 of 256 virtual cols)
  const int lrow = lane & 15;
  const int lkg = lane >> 4;

  // rect partition: flat -> (xcd, local); rect rid = xcd + 8*round; rect = 4mt x 8nt.
  // rounds share NG (B-group stays L2-hot), MG differs.
  const int flat = blockIdx.x;
  const int xcd = flat & 7, loc = flat >> 3;
  const int rnd = loc >> 5, w = loc & 31;
  const int rid = xcd + 8 * rnd;
  const int mt = (rid >> 2) * 4 + (w >> 3);
  const int nt = (rid & 3) * 8 + (w & 7);
  const int row0 = mt * 256, jb = nt * 128;

  // staging: chunk = 8 rows x 128B = 64 lanes x 16B; source col pre-swizzled so the
  // linear LDS write lands XOR-swizzled. Each wave stages 2 chunks per half-tile.
  const int cr = lane >> 3;
  const int ce = 8 * ((lane & 7) ^ cr);

  auto stA = [&](int buf, int h, int kk) {  // A half h: rows row0 + h*128 ..
#pragma unroll
    for (int i = 0; i < 2; ++i) {
      const int c = wid * 2 + i;
      gload16(fnb + (size_t)(row0 + h * 128 + c * 8 + cr) * DD + kk + ce,
              lA + buf * 16384 + h * 8192 + c * 512);
    }
  };
  auto stB = [&](int buf, int h, int kk) {  // h=0: fob -> vrows 0-127; h=1: fnb -> 128-255
    const u16* src = h ? fnb : fob;
#pragma unroll
    for (int i = 0; i < 2; ++i) {
      const int c = wid * 2 + i;
      gload16(src + (size_t)(jb + c * 8 + cr) * DD + kk + ce,
              lB + buf * 16384 + h * 8192 + c * 512);
    }
  };

  f32x4 acc[8][4];
#pragma unroll
  for (int a = 0; a < 8; ++a)
#pragma unroll
    for (int b = 0; b < 4; ++b) acc[a][b] = (f32x4)(0.0f);
  bf16x8 av[4], bv[4];

#define DSA(ks, mh)                                                              \
  {                                                                              \
    _Pragma("unroll") for (int mf = 0; mf < 4; ++mf) {                           \
      const int ar = wm * 128 + (mh) * 64 + mf * 16 + lrow;                      \
      const int bc = (ks) * 64 + lkg * 16;                                       \
      av[mf] = *(const bf16x8*)(cA + ar * 128 + (bc ^ ((ar & 7) << 4)));         \
    }                                                                            \
  }
#define DSB(ks)                                                                  \
  {                                                                              \
    _Pragma("unroll") for (int nf = 0; nf < 4; ++nf) {                           \
      const int br = wn * 64 + nf * 16 + lrow;                                   \
      const int bc = (ks) * 64 + lkg * 16;                                       \
      bv[nf] = *(const bf16x8*)(cB + br * 128 + (bc ^ ((br & 7) << 4)));         \
    }                                                                            \
  }
#define MFM(mh)                                                                  \
  {                                                                              \
    __builtin_amdgcn_s_setprio(1);                                               \
    _Pragma("unroll") for (int mf = 0; mf < 4; ++mf)                             \
        _Pragma("unroll") for (int nf = 0; nf < 4; ++nf) acc[(mh) * 4 + mf][nf] =\
            __builtin_amdgcn_mfma_f32_16x16x32_bf16(av[mf], bv[nf],              \
                                                    acc[(mh) * 4 + mf][nf], 0, 0, 0); \
    __builtin_amdgcn_s_setprio(0);                                               \
  }

  // prologue: stage tile 0 (8 loads/thread)
  stA(0, 0, 0);
  stA(0, 1, 0);
  stB(0, 0, 0);
  stB(0, 1, 0);

  for (int t = 0; t < 8; ++t) {
    const int cur = t & 1, nxt = cur ^ 1;
    const int kk = (t + 1) * 64;
    const char* cA = (const char*)(lA + cur * 16384);
    const char* cB = (const char*)(lB + cur * 16384);

    // phase 0 (gate): publish tile t, prefetch A-half0 of t+1
    if (t < 7) {
      stA(nxt, 0, kk);
      asm volatile("s_waitcnt vmcnt(2)" ::: "memory");  // drain tile t's 8; 2 new fly on
    } else {
      asm volatile("s_waitcnt vmcnt(0)" ::: "memory");
    }
    barrier_raw();
    DSA(0, 0);
    DSB(0);
    __builtin_amdgcn_sched_barrier(0);
    MFM(0);
    barrier_raw();
    // phase 1
    DSA(0, 1);
    if (t < 7) stA(nxt, 1, kk);
    barrier_raw();
    __builtin_amdgcn_sched_barrier(0);
    MFM(1);
    barrier_raw();
    // phase 2
    DSA(1, 0);
    DSB(1);
    if (t < 7) stB(nxt, 0, kk);
    barrier_raw();
    __builtin_amdgcn_sched_barrier(0);
    MFM(0);
    barrier_raw();
    // phase 3
    DSA(1, 1);
    if (t < 7) stB(nxt, 1, kk);
    barrier_raw();
    __builtin_amdgcn_sched_barrier(0);
    MFM(1);
    barrier_raw();
  }
#undef DSA
#undef DSB
#undef MFM

  // ---- epilogue: masked exp2, col-reduce over 16 lanes, combine waves via LDS ----
  const bool isN2O = (wn < 2);
  int tc[4];
#pragma unroll
  for (int nf = 0; nf < 4; ++nf) tc[nf] = tgt[jb + (wn & 1) * 64 + nf * 16 + lrow];
  float* rsum = (float*)lA;  // [2(wm)][4(wn)][128] floats = 4KB, staging done
#pragma unroll
  for (int macc = 0; macc < 8; ++macc) {
#pragma unroll
    for (int reg = 0; reg < 4; ++reg) {
      const int gr = row0 + wm * 128 + macc * 16 + lkg * 4 + reg;
      const int trv = tgt[gr];
      float s = 0.0f;
#pragma unroll
      for (int nf = 0; nf < 4; ++nf) {
        const int gc = jb + (wn & 1) * 64 + nf * 16 + lrow;
        const float p = __builtin_amdgcn_exp2f(fmaf(acc[macc][nf][reg], CEXP, EOFF));
        // n2o: keep diagonal (stands in for the explicit pos column), drop same-label
        // n2n: drop all same-label (diagonal auto-dropped, labels equal)
        const bool keep = (trv != tc[nf]) || (isN2O && gr == gc);
        s += keep ? p : 0.0f;
      }
      s += __shfl_xor(s, 1);
      s += __shfl_xor(s, 2);
      s += __shfl_xor(s, 4);
      s += __shfl_xor(s, 8);
      if (lrow == 0) rsum[(wm * 4 + wn) * 128 + macc * 16 + lkg * 4 + reg] = s;
    }
  }
  barrier_raw();
  if (tid < 256) {
    const int wmg = tid >> 7, rl = tid & 127;
    const float v = rsum[(wmg * 4 + 0) * 128 + rl] + rsum[(wmg * 4 + 1) * 128 + rl] +
                    rsum[(wmg * 4 + 2) * 128 + rl] + rsum[(wmg * 4 + 3) * 128 + rl];
    partial[(size_t)(row0 + tid) * 32 + nt] = v;
  }
}

// ---------------- kernel 3: per-row finalize (32 blocks) ----------------
__global__ __launch_bounds__(256) void k_final(const float* __restrict__ partial,
                                               const float* __restrict__ pos,
                                               float* __restrict__ bsum) {
  const int t = threadIdx.x;
  const int r = blockIdx.x * 128 + (t >> 1);
  const int half = t & 1;
  const float4* p = (const float4*)(partial + (size_t)r * 32 + half * 16);
  float v = 0.0f;
#pragma unroll
  for (int q = 0; q < 4; ++q) {
    const float4 a = p[q];
    v += (a.x + a.y) + (a.z + a.w);
  }
  v += __shfl_xor(v, 1);  // combine the two halves of the row
  float contrib = (half == 0)
                      ? (LSE_BASE + __builtin_amdgcn_logf(v) * LN2 - 100.0f * pos[r])
                      : 0.0f;
  contrib = wave_sum(contrib);
  __shared__ float red[4];
  if ((t & 63) == 0) red[t >> 6] = contrib;
  __syncthreads();
  if (t == 0) bsum[blockIdx.x] = (red[0] + red[1]) + (red[2] + red[3]);
}

// ---------------- kernel 4: mean of 32 block sums ----------------
__global__ __launch_bounds__(64) void k_mean(const float* __restrict__ bsum,
                                             float* __restrict__ out) {
  float s = (threadIdx.x < 32) ? bsum[threadIdx.x] : 0.0f;
  s = wave_sum(s);
  if (threadIdx.x == 0) out[0] = s * (1.0f / (float)BB);
}

extern "C" void kernel_launch(void* const* d_in, const int* in_sizes, int n_in,
                              void* d_out, int out_size, void* d_ws, size_t ws_size,
                              hipStream_t stream) {
  const float* feat = (const float*)d_in[0];
  const float* feat_old = (const float*)d_in[1];
  const int* targets = (const int*)d_in[2];
  float* out = (float*)d_out;
  char* ws = (char*)d_ws;

  u16* fnb = (u16*)ws;                                           // 4 MB
  u16* fob = (u16*)(ws + 4u * 1024 * 1024);                      // 4 MB
  float* pos = (float*)(ws + 8u * 1024 * 1024);                  // 16 KB
  float* partial = (float*)(ws + 8u * 1024 * 1024 + 16 * 1024);  // 512 KB
  float* bsum = (float*)(ws + 8u * 1024 * 1024 + 544 * 1024);    // 128 B

  k_norm<<<BB / 4, 256, 0, stream>>>(feat, feat_old, fnb, fob, pos);
  k_fused<<<512, 512, 0, stream>>>(fnb, fob, targets, partial);
  k_final<<<32, 256, 0, stream>>>(partial, pos, bsum);
  k_mean<<<1, 64, 0, stream>>>(bsum, out);
}

// Round 6
// 62.793 us; speedup vs baseline: 1.0328x; 1.0328x over previous
//
#include <hip/hip_runtime.h>
#include <hip/hip_bf16.h>

#define BB 4096
#define DD 512

typedef unsigned short u16;
typedef unsigned int u32;

using f32x4 = __attribute__((ext_vector_type(4))) float;
using bf16x8 = __attribute__((ext_vector_type(8))) short;

// exp scaling: p = exp2((s-1)*100*log2e + 64)  -> all normal-range for s in [-0.44, 1]
// lse = 100 - 64*ln2 + ln(sum p)
constexpr float CEXP = 144.26950408889634f;          // 100 * log2(e)
constexpr float EOFF = 64.0f - 144.26950408889634f;  // bias - CEXP
constexpr float LN2 = 0.6931471805599453f;
constexpr float LSE_BASE = 100.0f - 64.0f * 0.6931471805599453f;

__device__ __forceinline__ float wave_sum(float v) {
#pragma unroll
  for (int m = 1; m < 64; m <<= 1) v += __shfl_xor(v, m);
  return v;
}

__device__ __forceinline__ u16 f2bf(float f) {
  __hip_bfloat16 h = __float2bfloat16(f);
  return __builtin_bit_cast(u16, h);
}

// async global->LDS, 16B per lane. LDS dest must be wave-uniform; HW adds lane*16.
__device__ __forceinline__ void gload16(const u16* g, const u16* l) {
  __builtin_amdgcn_global_load_lds(
      (const __attribute__((address_space(1))) void*)g,
      (__attribute__((address_space(3))) void*)(const_cast<u16*>(l)), 16, 0, 0);
}

// raw barrier (no vmcnt/lgkmcnt drain); memory clobbers pin LDS ops to their side
__device__ __forceinline__ void barrier_raw() {
  asm volatile("" ::: "memory");
  __builtin_amdgcn_s_barrier();
  asm volatile("" ::: "memory");
}

// gate: per-wave counted vmcnt wait, then all-wave barrier => tile landed everywhere
#define GATE(VM)                                              \
  do {                                                        \
    asm volatile("s_waitcnt vmcnt(" #VM ")" ::: "memory");    \
    barrier_raw();                                            \
  } while (0)

// ---------------- kernel 1: row L2-normalize (fp32) -> bf16, plus fp32 pos ----------------
__global__ __launch_bounds__(256) void k_norm(const float* __restrict__ feat,
                                              const float* __restrict__ feat_old,
                                              u16* __restrict__ fnb, u16* __restrict__ fob,
                                              float* __restrict__ pos) {
  const int i = blockIdx.x * 4 + (threadIdx.x >> 6);
  const int t = threadIdx.x & 63;
  const float4 x0 = *(const float4*)(feat + (size_t)i * DD + t * 4);
  const float4 x1 = *(const float4*)(feat + (size_t)i * DD + 256 + t * 4);
  const float4 y0 = *(const float4*)(feat_old + (size_t)i * DD + t * 4);
  const float4 y1 = *(const float4*)(feat_old + (size_t)i * DD + 256 + t * 4);
  float sx = x0.x * x0.x + x0.y * x0.y + x0.z * x0.z + x0.w * x0.w +
             x1.x * x1.x + x1.y * x1.y + x1.z * x1.z + x1.w * x1.w;
  float sy = y0.x * y0.x + y0.y * y0.y + y0.z * y0.z + y0.w * y0.w +
             y1.x * y1.x + y1.y * y1.y + y1.z * y1.z + y1.w * y1.w;
  float sxy = x0.x * y0.x + x0.y * y0.y + x0.z * y0.z + x0.w * y0.w +
              x1.x * y1.x + x1.y * y1.y + x1.z * y1.z + x1.w * y1.w;
  sx = wave_sum(sx);
  sy = wave_sum(sy);
  sxy = wave_sum(sxy);
  const float inx = 1.0f / fmaxf(sqrtf(sx), 1e-12f);
  const float iny = 1.0f / fmaxf(sqrtf(sy), 1e-12f);
  ushort4 ox0, ox1, oy0, oy1;
  ox0.x = f2bf(x0.x * inx); ox0.y = f2bf(x0.y * inx);
  ox0.z = f2bf(x0.z * inx); ox0.w = f2bf(x0.w * inx);
  ox1.x = f2bf(x1.x * inx); ox1.y = f2bf(x1.y * inx);
  ox1.z = f2bf(x1.z * inx); ox1.w = f2bf(x1.w * inx);
  oy0.x = f2bf(y0.x * iny); oy0.y = f2bf(y0.y * iny);
  oy0.z = f2bf(y0.z * iny); oy0.w = f2bf(y0.w * iny);
  oy1.x = f2bf(y1.x * iny); oy1.y = f2bf(y1.y * iny);
  oy1.z = f2bf(y1.z * iny); oy1.w = f2bf(y1.w * iny);
  *(ushort4*)(fnb + (size_t)i * DD + t * 4) = ox0;
  *(ushort4*)(fnb + (size_t)i * DD + 256 + t * 4) = ox1;
  *(ushort4*)(fob + (size_t)i * DD + t * 4) = oy0;
  *(ushort4*)(fob + (size_t)i * DD + 256 + t * 4) = oy1;
  if (t == 0) pos[i] = sxy * inx * iny;
}

// ---------------- kernel 2: fused dual-GEMM, 4-slot ring pipeline ----------------
// 512 blocks; XCD-rect partition (rect = 4mt x 8nt = 3MB, L2-fit; FETCH ~14MB proven R5).
// 512 threads = 8 waves (2M x 4N); per-wave output 128x64 of the 256x256 virtual tile
// (vcols 0-127 = fob = n2o, 128-255 = fnb = n2n). BK=32, 16 K-tiles.
// LDS: ring of 4 x 32KB K-tile slots. While computing tile t (slot t&3), stage tile
// t+3 into slot (t+3)&3 == (t-1)&3, whose reads completed before this tile's gate
// barrier -> race-free for arbitrary wave drift. ONE barrier per K-tile; vmcnt(8)
// keeps 2 tiles' loads in flight across it (tail 8->4->0).
__global__ __launch_bounds__(512, 2) void k_fused(const u16* __restrict__ fnb,
                                                  const u16* __restrict__ fob,
                                                  const int* __restrict__ tgt,
                                                  float* __restrict__ partial) {
  __shared__ __align__(16) u16 lds[4 * 16384];  // 4 slots x (A 256x32 | B 256x32) = 128 KB

  const int tid = threadIdx.x;
  const int lane = tid & 63;
  const int wid = tid >> 6;  // 0..7
  const int wm = wid >> 2;   // 0..1  M half (128 rows)
  const int wn = wid & 3;    // 0..3  N quarter (64 of 256 virtual cols)
  const int lrow = lane & 15;
  const int lkg = lane >> 4;

  // rect partition: XCD x (blockIdx%8) owns rects {x, x+8}; rect = 4mt x 8nt
  const int flat = blockIdx.x;
  const int xcd = flat & 7, loc = flat >> 3;
  const int rnd = loc >> 5, w = loc & 31;
  const int rid = xcd + 8 * rnd;
  const int mt = (rid >> 2) * 4 + (w >> 3);
  const int nt = (rid & 3) * 8 + (w & 7);
  const int row0 = mt * 256, jb = nt * 128;

  // staging: one unit = 128 rows x 32 K = 8 KB = 512 threads x 16 B (1 gload/wave).
  // Source col pre-swizzled so linear LDS write lands in read-swizzled position:
  // physical slot p at row r holds logical slot p ^ ((r>>1)&3).
  const int srl = tid >> 2;                       // unit row 0..127
  const int ssl = (tid & 3) ^ ((srl >> 1) & 3);   // pre-swizzled source slot

  auto stage_unit = [&](const u16* src, int gr0, int kk, u32 ubase) {
    gload16(src + (size_t)(gr0 + srl) * DD + kk + ssl * 8, lds + ubase + (u32)wid * 512);
  };
  auto stage_tile = [&](int tt) {  // all 4 units of K-tile tt into slot tt&3
    const u32 ub = (u32)(tt & 3) * 16384u;
    const int kk = tt * 32;
    stage_unit(fnb, row0, kk, ub);                // A rows 0-127
    stage_unit(fnb, row0 + 128, kk, ub + 4096);   // A rows 128-255
    stage_unit(fob, jb, kk, ub + 8192);           // B vrows 0-127 (old)
    stage_unit(fnb, jb, kk, ub + 12288);          // B vrows 128-255 (new)
  };

  f32x4 acc[8][4];
#pragma unroll
  for (int a = 0; a < 8; ++a)
#pragma unroll
    for (int b = 0; b < 4; ++b) acc[a][b] = (f32x4)(0.0f);

  // read swizzle: row stride 64 B, slot' = lkg ^ ((row>>1)&3) -> 2 lanes/bank (free)
  auto kstep = [&](int t, bool doStage) {
    const char* Ab = (const char*)(lds + (u32)(t & 3) * 16384u);
    const char* Bb = Ab + 16384;  // bytes: B region at +8192 u16
    bf16x8 av[4], bv[4];
#pragma unroll
    for (int mf = 0; mf < 4; ++mf) {
      const int ar = wm * 128 + mf * 16 + lrow;
      av[mf] = *(const bf16x8*)(Ab + ar * 64 + ((lkg ^ ((ar >> 1) & 3)) * 16));
    }
#pragma unroll
    for (int nf = 0; nf < 4; ++nf) {
      const int br = wn * 64 + nf * 16 + lrow;
      bv[nf] = *(const bf16x8*)(Bb + br * 64 + ((lkg ^ ((br >> 1) & 3)) * 16));
    }
    if (doStage) {
      const u32 ub = (u32)((t + 3) & 3) * 16384u;
      const int kk = (t + 3) * 32;
      stage_unit(fnb, row0, kk, ub);
      stage_unit(fnb, row0 + 128, kk, ub + 4096);
    }
    __builtin_amdgcn_s_setprio(1);
#pragma unroll
    for (int mf = 0; mf < 4; ++mf)
#pragma unroll
      for (int nf = 0; nf < 4; ++nf)
        acc[mf][nf] = __builtin_amdgcn_mfma_f32_16x16x32_bf16(av[mf], bv[nf], acc[mf][nf], 0, 0, 0);
    __builtin_amdgcn_s_setprio(0);
    // second M-half; bv reused
#pragma unroll
    for (int mf = 0; mf < 4; ++mf) {
      const int ar = wm * 128 + 64 + mf * 16 + lrow;
      av[mf] = *(const bf16x8*)(Ab + ar * 64 + ((lkg ^ ((ar >> 1) & 3)) * 16));
    }
    if (doStage) {
      const u32 ub = (u32)((t + 3) & 3) * 16384u;
      const int kk = (t + 3) * 32;
      stage_unit(fob, jb, kk, ub + 8192);
      stage_unit(fnb, jb, kk, ub + 12288);
    }
    __builtin_amdgcn_s_setprio(1);
#pragma unroll
    for (int mf = 0; mf < 4; ++mf)
#pragma unroll
      for (int nf = 0; nf < 4; ++nf)
        acc[4 + mf][nf] = __builtin_amdgcn_mfma_f32_16x16x32_bf16(av[mf], bv[nf], acc[4 + mf][nf], 0, 0, 0);
    __builtin_amdgcn_s_setprio(0);
  };

  // prologue: stage tiles 0,1,2 (12 wave-loads in flight)
  stage_tile(0);
  stage_tile(1);
  stage_tile(2);

  for (int t = 0; t < 13; ++t) {  // stages tiles 3..15
    GATE(8);
    kstep(t, true);
  }
  GATE(8);
  kstep(13, false);
  GATE(4);
  kstep(14, false);
  GATE(0);
  kstep(15, false);

  // ---- epilogue: masked exp2, col-reduce over 16 lanes, combine waves via LDS ----
  const bool isN2O = (wn < 2);
  int tc[4];
#pragma unroll
  for (int nf = 0; nf < 4; ++nf) tc[nf] = tgt[jb + (wn & 1) * 64 + nf * 16 + lrow];
  float* rsum = (float*)lds;  // [2(wm)][4(wn)][128] floats = 4KB; slot-0 reads long done
#pragma unroll
  for (int macc = 0; macc < 8; ++macc) {
#pragma unroll
    for (int reg = 0; reg < 4; ++reg) {
      const int gr = row0 + wm * 128 + macc * 16 + lkg * 4 + reg;
      const int trv = tgt[gr];
      float s = 0.0f;
#pragma unroll
      for (int nf = 0; nf < 4; ++nf) {
        const int gc = jb + (wn & 1) * 64 + nf * 16 + lrow;
        const float p = __builtin_amdgcn_exp2f(fmaf(acc[macc][nf][reg], CEXP, EOFF));
        // n2o: keep diagonal (stands in for the explicit pos column), drop same-label
        // n2n: drop all same-label (diagonal auto-dropped, labels equal)
        const bool keep = (trv != tc[nf]) || (isN2O && gr == gc);
        s += keep ? p : 0.0f;
      }
      s += __shfl_xor(s, 1);
      s += __shfl_xor(s, 2);
      s += __shfl_xor(s, 4);
      s += __shfl_xor(s, 8);
      if (lrow == 0) rsum[(wm * 4 + wn) * 128 + macc * 16 + lkg * 4 + reg] = s;
    }
  }
  asm volatile("s_waitcnt lgkmcnt(0)" ::: "memory");
  barrier_raw();
  if (tid < 256) {
    const int wmg = tid >> 7, rl = tid & 127;
    const float v = rsum[(wmg * 4 + 0) * 128 + rl] + rsum[(wmg * 4 + 1) * 128 + rl] +
                    rsum[(wmg * 4 + 2) * 128 + rl] + rsum[(wmg * 4 + 3) * 128 + rl];
    partial[(size_t)(row0 + tid) * 32 + nt] = v;
  }
}

// ---------------- kernel 3: per-row finalize (32 blocks) ----------------
__global__ __launch_bounds__(256) void k_final(const float* __restrict__ partial,
                                               const float* __restrict__ pos,
                                               float* __restrict__ bsum) {
  const int t = threadIdx.x;
  const int r = blockIdx.x * 128 + (t >> 1);
  const int half = t & 1;
  const float4* p = (const float4*)(partial + (size_t)r * 32 + half * 16);
  float v = 0.0f;
#pragma unroll
  for (int q = 0; q < 4; ++q) {
    const float4 a = p[q];
    v += (a.x + a.y) + (a.z + a.w);
  }
  v += __shfl_xor(v, 1);  // combine the two halves of the row
  float contrib = (half == 0)
                      ? (LSE_BASE + __builtin_amdgcn_logf(v) * LN2 - 100.0f * pos[r])
                      : 0.0f;
  contrib = wave_sum(contrib);
  __shared__ float red[4];
  if ((t & 63) == 0) red[t >> 6] = contrib;
  __syncthreads();
  if (t == 0) bsum[blockIdx.x] = (red[0] + red[1]) + (red[2] + red[3]);
}

// ---------------- kernel 4: mean of 32 block sums ----------------
__global__ __launch_bounds__(64) void k_mean(const float* __restrict__ bsum,
                                             float* __restrict__ out) {
  float s = (threadIdx.x < 32) ? bsum[threadIdx.x] : 0.0f;
  s = wave_sum(s);
  if (threadIdx.x == 0) out[0] = s * (1.0f / (float)BB);
}

extern "C" void kernel_launch(void* const* d_in, const int* in_sizes, int n_in,
                              void* d_out, int out_size, void* d_ws, size_t ws_size,
                              hipStream_t stream) {
  const float* feat = (const float*)d_in[0];
  const float* feat_old = (const float*)d_in[1];
  const int* targets = (const int*)d_in[2];
  float* out = (float*)d_out;
  char* ws = (char*)d_ws;

  u16* fnb = (u16*)ws;                                           // 4 MB
  u16* fob = (u16*)(ws + 4u * 1024 * 1024);                      // 4 MB
  float* pos = (float*)(ws + 8u * 1024 * 1024);                  // 16 KB
  float* partial = (float*)(ws + 8u * 1024 * 1024 + 16 * 1024);  // 512 KB
  float* bsum = (float*)(ws + 8u * 1024 * 1024 + 544 * 1024);    // 128 B

  k_norm<<<BB / 4, 256, 0, stream>>>(feat, feat_old, fnb, fob, pos);
  k_fused<<<512, 512, 0, stream>>>(fnb, fob, targets, partial);
  k_final<<<32, 256, 0, stream>>>(partial, pos, bsum);
  k_mean<<<1, 64, 0, stream>>>(bsum, out);
}